// Round 6
// baseline (150.587 us; speedup 1.0000x reference)
//
#include <hip/hip_runtime.h>
#include <stdint.h>

#define HH 8192           // B*H = 16*512 strip height
#define WW 512            // width
#define WPR 8             // uint64 words per row (512/64)
#define TG22F 0.4142135623730951f
#define NROUND 8          // cap; early-exits on convergence
#define NBLK 32           // hysteresis-active blocks (128 waves x 64-row bands)
#define TBLK 512          // cooperative grid (2 blocks/CU at <=256 VGPR -> co-resident)

// ---- workspace layout (bytes) ----
// packed u16 mag|dir<<12 : 8 MiB   @ 0
// buf (strong, in-place) : 512 KiB @ 8388608
// weak bitmap            : 512 KiB @ 8912896
// flags (32 ints)        : 128 B   @ 9437184
//   flags[0..7]  = per-round "grew" indicators
//   flags[8..15] = per-round hyst barrier counters (count to NBLK)
//   flags[16]    = grid barrier A counter (count to TBLK)
//   flags[17]    = grid barrier B counter (count to TBLK)
// flags are zeroed by k_sobel (prior dispatch) -> no zero-vs-arrive race.

__device__ __forceinline__ float to_img(float v) {
    float t = floorf((v + 1.0f) * 0.5f * 255.0f);
    return fminf(fmaxf(t, 0.0f), 255.0f);
}

__device__ __forceinline__ int bsel(uint64_t w0, uint64_t w1, int idx) {
    return (idx < 8) ? (int)((w0 >> (idx * 8)) & 255)
                     : (int)((w1 >> ((idx - 8) * 8)) & 255);
}

// Fill all bits of runs of `w` that contain at least one bit of `s`.
__device__ __forceinline__ uint64_t runfill(uint64_t s, uint64_t w) {
    uint64_t sw = s & w;
    uint64_t up = ((sw + w) ^ w) & w;
    uint64_t rs = __brevll(sw);
    uint64_t rw = __brevll(w);
    uint64_t dn = __brevll(((rs + rw) ^ rw) & rw);
    return up | dn | sw;
}

// 64-bit shuffles via two 32-bit halves (avoid 64-bit shfl overloads).
__device__ __forceinline__ uint64_t shfl_up64(uint64_t v, int d) {
    int lo = __shfl_up((int)(uint32_t)v, d, 64);
    int hi = __shfl_up((int)(uint32_t)(v >> 32), d, 64);
    return ((uint64_t)(uint32_t)hi << 32) | (uint32_t)lo;
}
__device__ __forceinline__ uint64_t shfl_dn64(uint64_t v, int d) {
    int lo = __shfl_down((int)(uint32_t)v, d, 64);
    int hi = __shfl_down((int)(uint32_t)(v >> 32), d, 64);
    return ((uint64_t)(uint32_t)hi << 32) | (uint32_t)lo;
}

// coherent (cache-bypassing) 64-bit load/store at agent scope, no fences
__device__ __forceinline__ uint64_t cload64(const unsigned long long* p) {
    return __hip_atomic_load((const unsigned long long*)p, __ATOMIC_RELAXED,
                             __HIP_MEMORY_SCOPE_AGENT);
}
__device__ __forceinline__ void cstore64(unsigned long long* p, uint64_t v) {
    __hip_atomic_store(p, (unsigned long long)v, __ATOMIC_RELAXED,
                       __HIP_MEMORY_SCOPE_AGENT);
}

// grid barrier: vmcnt(0) drained by __syncthreads before the arrive add;
// relaxed coherent counter, sleep-spin (verified pattern from k_hyst).
__device__ __forceinline__ void gbar(int* flags, int slot, int target) {
    __syncthreads();
    if (threadIdx.x == 0) {
        __hip_atomic_fetch_add(&flags[slot], 1, __ATOMIC_RELAXED, __HIP_MEMORY_SCOPE_AGENT);
        while (__hip_atomic_load(&flags[slot], __ATOMIC_RELAXED, __HIP_MEMORY_SCOPE_AGENT) < target)
            __builtin_amdgcn_s_sleep(2);
    }
    __syncthreads();
}

// Kernel 1: quantize + Sobel (replicate pad on strip) + channel argmax + dir.
// (verbatim verified version; additionally zeroes the 32 flag ints)
__global__ void k_sobel(const float* __restrict__ in, uint16_t* __restrict__ packed,
                        int* __restrict__ flags) {
    __shared__ uint8_t simg[3 * 34 * 72];
    const int tid = threadIdx.x;
    const int row0 = (blockIdx.x >> 3) << 5;
    const int col0 = (blockIdx.x & 7) << 6;

    if (blockIdx.x == 0 && tid < 32) flags[tid] = 0;

    for (int i = tid; i < 1632; i += 256) {
        int c = i / 544;
        int rem = i - c * 544;
        int hr = rem >> 4;
        int q = rem & 15;
        int gy = row0 + hr - 1;
        gy = gy < 0 ? 0 : (gy >= HH ? HH - 1 : gy);
        int b = gy >> 9, h = gy & 511;
        const float4 v = *(const float4*)&in[((((b * 3 + c) << 9) + h) << 9) + col0 + (q << 2)];
        uint32_t pk = (uint32_t)(uint8_t)to_img(v.x)
                    | ((uint32_t)(uint8_t)to_img(v.y) << 8)
                    | ((uint32_t)(uint8_t)to_img(v.z) << 16)
                    | ((uint32_t)(uint8_t)to_img(v.w) << 24);
        *(uint32_t*)&simg[(c * 34 + hr) * 72 + 4 + (q << 2)] = pk;
    }
    for (int i = tid; i < 204; i += 256) {
        int c = i / 68;
        int rem = i - c * 68;
        int hr = rem >> 1;
        int side = rem & 1;
        int gy = row0 + hr - 1;
        gy = gy < 0 ? 0 : (gy >= HH ? HH - 1 : gy);
        int gc = side ? col0 + 64 : col0 - 1;
        gc = gc < 0 ? 0 : (gc >= WW ? WW - 1 : gc);
        int b = gy >> 9, h = gy & 511;
        float v = to_img(in[((((b * 3 + c) << 9) + h) << 9) + gc]);
        simg[(c * 34 + hr) * 72 + (side ? 68 : 3)] = (uint8_t)v;
    }
    __syncthreads();

    const int r = tid >> 3;
    const int c8 = (tid & 7) << 3;

    int bestMag[8], bgx[8], bgy[8];
    #pragma unroll
    for (int j = 0; j < 8; ++j) { bestMag[j] = -1; bgx[j] = 0; bgy[j] = 0; }

    #pragma unroll
    for (int c = 0; c < 3; ++c) {
        const uint8_t* base = &simg[(c * 34 + r) * 72 + c8];
        uint64_t w00 = *(const uint64_t*)(base);
        uint64_t w01 = *(const uint64_t*)(base + 8);
        uint64_t w10 = *(const uint64_t*)(base + 72);
        uint64_t w11 = *(const uint64_t*)(base + 80);
        uint64_t w20 = *(const uint64_t*)(base + 144);
        uint64_t w21 = *(const uint64_t*)(base + 152);
        int vs[10], t0[10], t2[10];
        #pragma unroll
        for (int i = 0; i < 10; ++i) {
            int a0 = bsel(w00, w01, 3 + i);
            int a1 = bsel(w10, w11, 3 + i);
            int a2 = bsel(w20, w21, 3 + i);
            vs[i] = a0 + 2 * a1 + a2;
            t0[i] = a0; t2[i] = a2;
        }
        #pragma unroll
        for (int j = 0; j < 8; ++j) {
            int gx = vs[j + 2] - vs[j];
            int gy = (t2[j] + 2 * t2[j + 1] + t2[j + 2]) - (t0[j] + 2 * t0[j + 1] + t0[j + 2]);
            int mg = abs(gx) + abs(gy);
            if (mg > bestMag[j]) { bestMag[j] = mg; bgx[j] = gx; bgy[j] = gy; }
        }
    }

    uint32_t res[4];
    #pragma unroll
    for (int jj = 0; jj < 4; ++jj) {
        uint32_t pair = 0;
        #pragma unroll
        for (int s = 0; s < 2; ++s) {
            int j = jj * 2 + s;
            float axf = (float)abs(bgx[j]);
            float ayf = (float)abs(bgy[j]);
            int dir;
            if (ayf < TG22F * axf)      dir = 0;
            else if (ayf * TG22F > axf) dir = 1;
            else                        dir = (bgx[j] * bgy[j] >= 0) ? 2 : 3;
            uint32_t val = (uint32_t)(bestMag[j] | (dir << 12));
            pair |= val << (s * 16);
        }
        res[jj] = pair;
    }
    int y = row0 + r;
    *(uint4*)&packed[y * WW + col0 + c8] = *(uint4*)res;
}

// extract mag (12 bits) of px idx (0..7, compile-time) from a row quad (lo,hi)
#define MEXT(lo, hi, idx) ((int)((((idx) < 4 ? ((lo) >> (16 * (idx))) \
                                             : ((hi) >> (16 * ((idx) - 4))))) & 0xFFF))

// wave-row NMS for row y (verbatim round-5 verified math). Bitmap words are
// written with coherent stores (read cross-XCD later in the same kernel).
__device__ __forceinline__ void nms_row(int y, int lane,
        const uint16_t* __restrict__ packed,
        unsigned long long* __restrict__ strongB,
        unsigned long long* __restrict__ weakB) {
    uint4 q = *(const uint4*)&packed[y * WW + (lane << 3)];
    uint64_t oLo = ((uint64_t)q.y << 32) | q.x;
    uint64_t oHi = ((uint64_t)q.w << 32) | q.z;
    uint64_t uLo = 0, uHi = 0, dLo = 0, dHi = 0;
    if (y > 0) {
        uint4 qu = *(const uint4*)&packed[(y - 1) * WW + (lane << 3)];
        uLo = ((uint64_t)qu.y << 32) | qu.x;
        uHi = ((uint64_t)qu.w << 32) | qu.z;
    }
    if (y < HH - 1) {
        uint4 qd = *(const uint4*)&packed[(y + 1) * WW + (lane << 3)];
        dLo = ((uint64_t)qd.y << 32) | qd.x;
        dHi = ((uint64_t)qd.w << 32) | qd.z;
    }

    int oL = __shfl_up((int)((oHi >> 48) & 0xFFF), 1, 64); if (lane == 0) oL = 0;
    int uL = __shfl_up((int)((uHi >> 48) & 0xFFF), 1, 64); if (lane == 0) uL = 0;
    int dL = __shfl_up((int)((dHi >> 48) & 0xFFF), 1, 64); if (lane == 0) dL = 0;
    int oR = __shfl_down((int)(oLo & 0xFFF), 1, 64); if (lane == 63) oR = 0;
    int uR = __shfl_down((int)(uLo & 0xFFF), 1, 64); if (lane == 63) uR = 0;
    int dR = __shfl_down((int)(dLo & 0xFFF), 1, 64); if (lane == 63) dR = 0;

    uint32_t sb = 0, wb = 0;
    #pragma unroll
    for (int i = 0; i < 8; ++i) {
        int raw = (int)(((i < 4 ? (oLo >> (16 * i)) : (oHi >> (16 * (i - 4))))) & 0xFFFF);
        int m = raw & 0xFFF;
        int dir = raw >> 12;
        int Om1 = (i == 0) ? oL : MEXT(oLo, oHi, (i == 0 ? 0 : i - 1));
        int Op1 = (i == 7) ? oR : MEXT(oLo, oHi, (i == 7 ? 7 : i + 1));
        int Ui  = MEXT(uLo, uHi, i);
        int Um1 = (i == 0) ? uL : MEXT(uLo, uHi, (i == 0 ? 0 : i - 1));
        int Up1 = (i == 7) ? uR : MEXT(uLo, uHi, (i == 7 ? 7 : i + 1));
        int Di  = MEXT(dLo, dHi, i);
        int Dm1 = (i == 0) ? dL : MEXT(dLo, dHi, (i == 0 ? 0 : i - 1));
        int Dp1 = (i == 7) ? dR : MEXT(dLo, dHi, (i == 7 ? 7 : i + 1));
        int n1 = (dir == 0) ? Om1 : (dir == 1) ? Ui : (dir == 2) ? Um1 : Up1;
        int n2 = (dir == 0) ? Op1 : (dir == 1) ? Di : (dir == 2) ? Dp1 : Dm1;
        bool keep = (m > n1) && (m >= n2);
        if (keep && m > 200) sb |= 1u << i;
        if (keep && m > 100) wb |= 1u << i;
    }

    const int src = (lane & 7) << 3;
    uint64_t wordS = 0, wordW = 0;
    #pragma unroll
    for (int i = 0; i < 8; ++i) {
        wordS |= (uint64_t)(uint32_t)__shfl((int)sb, src + i, 64) << (i * 8);
        wordW |= (uint64_t)(uint32_t)__shfl((int)wb, src + i, 64) << (i * 8);
    }
    if (lane < 8)       cstore64(&strongB[y * WPR + lane], wordS);
    else if (lane < 16) cstore64(&weakB[y * WPR + (lane - 8)], wordW);
}

// expand one bitmap row -> 3 output channels, fully coalesced float4 stores.
__device__ __forceinline__ void out_row(int y, int lane,
        const unsigned long long* __restrict__ buf, float* __restrict__ out) {
    const int b = y >> 9, h = y & 511;
    const int obase = ((b * 3) << 18) + (h << 9);
    #pragma unroll
    for (int i = 0; i < 2; ++i) {
        int idx = lane + (i << 6);            // 0..127
        uint64_t wv = cload64(&buf[y * WPR + (idx >> 4)]);
        int x = idx << 2;                     // 0..508, step 4
        int sh = x & 63;
        float4 v;
        v.x = ((wv >> (sh + 0)) & 1ull) ? 1.0f : -1.0f;
        v.y = ((wv >> (sh + 1)) & 1ull) ? 1.0f : -1.0f;
        v.z = ((wv >> (sh + 2)) & 1ull) ? 1.0f : -1.0f;
        v.w = ((wv >> (sh + 3)) & 1ull) ? 1.0f : -1.0f;
        *(float4*)&out[obase + x] = v;
        *(float4*)&out[obase + (1 << 18) + x] = v;
        *(float4*)&out[obase + (2 << 18) + x] = v;
    }
}

// Kernel 2: NMS + hysteresis + output in ONE cooperative kernel.
// 512 blocks (2/CU worst case -> guaranteed co-resident). Grid barriers via
// relaxed coherent counters (flags pre-zeroed by k_sobel). Hysteresis phase
// runs on blocks 0..31 only (verified k_hyst body; loads/stores coherent).
__global__ void __launch_bounds__(256) k_nho(
        const uint16_t* __restrict__ packed,
        unsigned long long* __restrict__ buf,       // strongB, in-place hyst
        unsigned long long* __restrict__ weakB,
        int* __restrict__ flags,
        float* __restrict__ out)
{
    const int lane = threadIdx.x & 63;
    const int widx = threadIdx.x >> 6;
    const int wv = (blockIdx.x << 2) + widx;        // 0..2047

    // ---- Phase N: NMS, 4 rows per wave ----
    #pragma unroll
    for (int r = 0; r < 4; ++r)
        nms_row((wv << 2) + r, lane, packed, buf, weakB);

    gbar(flags, 16, TBLK);                          // barrier A

    // ---- Phase H: hysteresis on blocks 0..31 (verbatim verified body) ----
    if (blockIdx.x < NBLK) {
        const int wave = (blockIdx.x << 2) + widx;  // 0..127
        const int base = ((wave << 6) + lane) * WPR;

        uint64_t own[8], wk[8];
        #pragma unroll
        for (int k = 0; k < 8; ++k) {
            wk[k]  = cload64(&weakB[base + k]);
            own[k] = cload64(&buf[base + k]);
        }

        uint64_t hspu[8], hspd[8];
        #pragma unroll
        for (int k = 0; k < 8; ++k) { hspu[k] = 0; hspd[k] = 0; }

        auto load_halo = [&]() {
            uint64_t h[8];
            if (lane == 0 && wave > 0) {
                #pragma unroll
                for (int k = 0; k < 8; ++k) h[k] = cload64(&buf[base - WPR + k]);
                #pragma unroll
                for (int k = 0; k < 8; ++k) {
                    uint64_t a = h[k] | (h[k] << 1) | (h[k] >> 1);
                    if (k > 0) a |= h[k - 1] >> 63;
                    if (k < 7) a |= h[k + 1] << 63;
                    hspu[k] = a;
                }
            }
            if (lane == 63 && wave < 127) {
                #pragma unroll
                for (int k = 0; k < 8; ++k) h[k] = cload64(&buf[base + WPR + k]);
                #pragma unroll
                for (int k = 0; k < 8; ++k) {
                    uint64_t a = h[k] | (h[k] << 1) | (h[k] >> 1);
                    if (k > 0) a |= h[k - 1] >> 63;
                    if (k < 7) a |= h[k + 1] << 63;
                    hspd[k] = a;
                }
            }
        };
        load_halo();

        bool grewAny = false;
        for (int r = 0; r < NROUND; ++r) {
            bool grew = false;
            for (;;) {
                uint64_t sp[8];
                #pragma unroll
                for (int k = 0; k < 8; ++k) {
                    uint64_t h = own[k] | (own[k] << 1) | (own[k] >> 1);
                    if (k > 0) h |= own[k - 1] >> 63;
                    if (k < 7) h |= own[k + 1] << 63;
                    sp[k] = h;
                }
                uint64_t su[8], sd[8];
                #pragma unroll
                for (int k = 0; k < 8; ++k) {
                    su[k] = shfl_up64(sp[k], 1);
                    sd[k] = shfl_dn64(sp[k], 1);
                }
                if (lane == 0) {
                    #pragma unroll
                    for (int k = 0; k < 8; ++k) su[k] = hspu[k];
                }
                if (lane == 63) {
                    #pragma unroll
                    for (int k = 0; k < 8; ++k) sd[k] = hspd[k];
                }
                uint32_t ch = 0;
                #pragma unroll
                for (int k = 0; k < 8; ++k) {
                    uint64_t acc = sp[k] | su[k] | sd[k];
                    uint64_t nv = runfill(own[k] | (acc & wk[k]), wk[k]);
                    ch |= (uint32_t)(nv != own[k]);
                    own[k] = nv;
                }
                if (ch) grew = true;
                if (__ballot(ch ? 1 : 0) == 0ull) break;   // wave-uniform
            }
            grewAny |= grew;

            if (grew && lane == 0)
                __hip_atomic_store(&flags[r], 1, __ATOMIC_RELAXED, __HIP_MEMORY_SCOPE_AGENT);
            if (lane == 0 || lane == 63) {
                #pragma unroll
                for (int k = 0; k < 8; ++k) cstore64(&buf[base + k], own[k]);
            }
            __syncthreads();
            if (threadIdx.x == 0) {
                __hip_atomic_fetch_add(&flags[8 + r], 1, __ATOMIC_RELAXED, __HIP_MEMORY_SCOPE_AGENT);
                while (__hip_atomic_load(&flags[8 + r], __ATOMIC_RELAXED, __HIP_MEMORY_SCOPE_AGENT) < NBLK)
                    __builtin_amdgcn_s_sleep(2);
            }
            __syncthreads();

            if (__hip_atomic_load(&flags[r], __ATOMIC_RELAXED, __HIP_MEMORY_SCOPE_AGENT) == 0)
                break;
            if (r + 1 < NROUND) load_halo();
        }

        // final writeback: coherent (same-kernel cross-XCD readers in phase O)
        if (__ballot(grewAny ? 1 : 0) != 0ull) {
            #pragma unroll
            for (int k = 0; k < 8; ++k) cstore64(&buf[base + k], own[k]);
        }
    }

    gbar(flags, 17, TBLK);                          // barrier B

    // ---- Phase O: expand bitmap -> output, 4 rows per wave ----
    #pragma unroll
    for (int r = 0; r < 4; ++r)
        out_row((wv << 2) + r, lane, buf, out);
}

extern "C" void kernel_launch(void* const* d_in, const int* in_sizes, int n_in,
                              void* d_out, int out_size, void* d_ws, size_t ws_size,
                              hipStream_t stream) {
    const float* x = (const float*)d_in[0];
    float* out = (float*)d_out;
    char* ws = (char*)d_ws;

    uint16_t* packed          = (uint16_t*)(ws);
    unsigned long long* buf   = (unsigned long long*)(ws + 8388608);
    unsigned long long* weakB = (unsigned long long*)(ws + 8912896);
    int* flags                = (int*)(ws + 9437184);

    k_sobel<<<2048, 256, 0, stream>>>(x, packed, flags);
    k_nho<<<TBLK, 256, 0, stream>>>(packed, buf, weakB, flags, out);
}

// Round 7
// 119.528 us; speedup vs baseline: 1.2598x; 1.2598x over previous
//
#include <hip/hip_runtime.h>
#include <stdint.h>

#define HH 8192           // B*H = 16*512 strip height
#define WW 512            // width
#define WPR 8             // uint64 words per row (512/64)
#define TG22F 0.4142135623730951f
#define NROUND 8          // cap; early-exits on convergence
#define NBLK 32           // hysteresis grid (co-resident: 32 blocks << 256 CUs)

// ---- workspace layout (bytes) ----
// packed u16 mag|dir<<12 : 8 MiB   @ 0
// buf (strong, in-place) : 512 KiB @ 8388608
// weak bitmap            : 512 KiB @ 8912896
// flags (16 ints)        : 64 B    @ 9437184
//   flags[0..7]  = per-round "grew" indicators
//   flags[8..15] = per-round grid-barrier arrive counters (single-use, no reset)

__device__ __forceinline__ float to_img(float v) {
    float t = floorf((v + 1.0f) * 0.5f * 255.0f);
    return fminf(fmaxf(t, 0.0f), 255.0f);
}

// Fill all bits of runs of `w` that contain at least one bit of `s`.
__device__ __forceinline__ uint64_t runfill(uint64_t s, uint64_t w) {
    uint64_t sw = s & w;
    uint64_t up = ((sw + w) ^ w) & w;
    uint64_t rs = __brevll(sw);
    uint64_t rw = __brevll(w);
    uint64_t dn = __brevll(((rs + rw) ^ rw) & rw);
    return up | dn | sw;
}

// 64-bit shuffles via two 32-bit halves (avoid 64-bit shfl overloads).
__device__ __forceinline__ uint64_t shfl_up64(uint64_t v, int d) {
    int lo = __shfl_up((int)(uint32_t)v, d, 64);
    int hi = __shfl_up((int)(uint32_t)(v >> 32), d, 64);
    return ((uint64_t)(uint32_t)hi << 32) | (uint32_t)lo;
}
__device__ __forceinline__ uint64_t shfl_dn64(uint64_t v, int d) {
    int lo = __shfl_down((int)(uint32_t)v, d, 64);
    int hi = __shfl_down((int)(uint32_t)(v >> 32), d, 64);
    return ((uint64_t)(uint32_t)hi << 32) | (uint32_t)lo;
}

// coherent (cache-bypassing) 64-bit load/store at agent scope, no fences
__device__ __forceinline__ uint64_t cload64(const unsigned long long* p) {
    return __hip_atomic_load((const unsigned long long*)p, __ATOMIC_RELAXED,
                             __HIP_MEMORY_SCOPE_AGENT);
}
__device__ __forceinline__ void cstore64(unsigned long long* p, uint64_t v) {
    __hip_atomic_store(p, (unsigned long long)v, __ATOMIC_RELAXED,
                       __HIP_MEMORY_SCOPE_AGENT);
}

// load 10 quantized pixels (cols 8*lane-1 .. 8*lane+8, edge-replicated) of
// one channel/row into a[0..9]. Two coalesced float4 loads + 2 shuffles.
__device__ __forceinline__ void load_row10(const float* __restrict__ in,
                                           int row, int c, int lane, int a[10]) {
    const float* p = &in[(size_t)((((row >> 9) * 3 + c) << 9) + (row & 511)) << 9];
    const int x0 = lane << 3;
    float4 v0 = *(const float4*)&p[x0];
    float4 v1 = *(const float4*)&p[x0 + 4];
    a[1] = (int)(uint8_t)to_img(v0.x);
    a[2] = (int)(uint8_t)to_img(v0.y);
    a[3] = (int)(uint8_t)to_img(v0.z);
    a[4] = (int)(uint8_t)to_img(v0.w);
    a[5] = (int)(uint8_t)to_img(v1.x);
    a[6] = (int)(uint8_t)to_img(v1.y);
    a[7] = (int)(uint8_t)to_img(v1.z);
    a[8] = (int)(uint8_t)to_img(v1.w);
    int l = __shfl_up(a[8], 1, 64);
    a[0] = (lane == 0) ? a[1] : l;      // col -1 -> replicate col 0
    int r = __shfl_down(a[1], 1, 64);
    a[9] = (lane == 63) ? a[8] : r;     // col 512 -> replicate col 511
}

// Kernel 1 (NEW): quantize + Sobel + channel argmax + dir, one WAVE per image
// row, 8 px/lane. No LDS, no barriers: 3 rows x 3 ch loaded straight from
// global (wave-uniform row bases, coalesced float4), edge pixels via 2
// shuffles/row. Row replicate-clamp on the strip and all arithmetic are
// verbatim the verified math -> bit-identical packed output.
__global__ void k_sobel(const float* __restrict__ in, uint16_t* __restrict__ packed) {
    const int lane = threadIdx.x & 63;
    const int y  = (blockIdx.x << 2) + (threadIdx.x >> 6);
    const int ym = (y > 0) ? y - 1 : 0;
    const int yp = (y < HH - 1) ? y + 1 : HH - 1;

    int bestMag[8], bgx[8], bgy[8];
    #pragma unroll
    for (int j = 0; j < 8; ++j) { bestMag[j] = -1; bgx[j] = 0; bgy[j] = 0; }

    #pragma unroll
    for (int c = 0; c < 3; ++c) {
        int a0[10], a1[10], a2[10];
        load_row10(in, ym, c, lane, a0);
        load_row10(in, y,  c, lane, a1);
        load_row10(in, yp, c, lane, a2);
        int vs[10];
        #pragma unroll
        for (int i = 0; i < 10; ++i) vs[i] = a0[i] + 2 * a1[i] + a2[i];
        #pragma unroll
        for (int j = 0; j < 8; ++j) {
            int gx = vs[j + 2] - vs[j];
            int gy = (a2[j] + 2 * a2[j + 1] + a2[j + 2]) - (a0[j] + 2 * a0[j + 1] + a0[j + 2]);
            int mg = abs(gx) + abs(gy);
            if (mg > bestMag[j]) { bestMag[j] = mg; bgx[j] = gx; bgy[j] = gy; }
        }
    }

    uint32_t res[4];
    #pragma unroll
    for (int jj = 0; jj < 4; ++jj) {
        uint32_t pair = 0;
        #pragma unroll
        for (int s = 0; s < 2; ++s) {
            int j = jj * 2 + s;
            float axf = (float)abs(bgx[j]);
            float ayf = (float)abs(bgy[j]);
            int dir;
            if (ayf < TG22F * axf)      dir = 0;
            else if (ayf * TG22F > axf) dir = 1;
            else                        dir = (bgx[j] * bgy[j] >= 0) ? 2 : 3;
            uint32_t val = (uint32_t)(bestMag[j] | (dir << 12));
            pair |= val << (s * 16);
        }
        res[jj] = pair;
    }
    *(uint4*)&packed[y * WW + (lane << 3)] = *(uint4*)res;
}

// extract mag (12 bits) of px idx (0..7, compile-time) from a row quad (lo,hi)
#define MEXT(lo, hi, idx) ((int)((((idx) < 4 ? ((lo) >> (16 * (idx))) \
                                             : ((hi) >> (16 * ((idx) - 4))))) & 0xFFF))

// Kernel 2: NMS, one wave per image row, 8 px per lane. (verbatim round-5)
__global__ void k_nms(const uint16_t* __restrict__ packed,
                      unsigned long long* __restrict__ strongB,
                      unsigned long long* __restrict__ weakB,
                      int* __restrict__ flags) {
    if (blockIdx.x == 0 && threadIdx.x < 16) flags[threadIdx.x] = 0;
    const int lane = threadIdx.x & 63;
    const int w = threadIdx.x >> 6;
    const int y = (blockIdx.x << 2) + w;

    uint4 q = *(const uint4*)&packed[y * WW + (lane << 3)];
    uint64_t oLo = ((uint64_t)q.y << 32) | q.x;
    uint64_t oHi = ((uint64_t)q.w << 32) | q.z;
    uint64_t uLo = 0, uHi = 0, dLo = 0, dHi = 0;
    if (y > 0) {
        uint4 qu = *(const uint4*)&packed[(y - 1) * WW + (lane << 3)];
        uLo = ((uint64_t)qu.y << 32) | qu.x;
        uHi = ((uint64_t)qu.w << 32) | qu.z;
    }
    if (y < HH - 1) {
        uint4 qd = *(const uint4*)&packed[(y + 1) * WW + (lane << 3)];
        dLo = ((uint64_t)qd.y << 32) | qd.x;
        dHi = ((uint64_t)qd.w << 32) | qd.z;
    }

    int oL = __shfl_up((int)((oHi >> 48) & 0xFFF), 1, 64); if (lane == 0) oL = 0;
    int uL = __shfl_up((int)((uHi >> 48) & 0xFFF), 1, 64); if (lane == 0) uL = 0;
    int dL = __shfl_up((int)((dHi >> 48) & 0xFFF), 1, 64); if (lane == 0) dL = 0;
    int oR = __shfl_down((int)(oLo & 0xFFF), 1, 64); if (lane == 63) oR = 0;
    int uR = __shfl_down((int)(uLo & 0xFFF), 1, 64); if (lane == 63) uR = 0;
    int dR = __shfl_down((int)(dLo & 0xFFF), 1, 64); if (lane == 63) dR = 0;

    uint32_t sb = 0, wb = 0;
    #pragma unroll
    for (int i = 0; i < 8; ++i) {
        int raw = (int)(((i < 4 ? (oLo >> (16 * i)) : (oHi >> (16 * (i - 4))))) & 0xFFFF);
        int m = raw & 0xFFF;
        int dir = raw >> 12;
        int Om1 = (i == 0) ? oL : MEXT(oLo, oHi, (i == 0 ? 0 : i - 1));
        int Op1 = (i == 7) ? oR : MEXT(oLo, oHi, (i == 7 ? 7 : i + 1));
        int Ui  = MEXT(uLo, uHi, i);
        int Um1 = (i == 0) ? uL : MEXT(uLo, uHi, (i == 0 ? 0 : i - 1));
        int Up1 = (i == 7) ? uR : MEXT(uLo, uHi, (i == 7 ? 7 : i + 1));
        int Di  = MEXT(dLo, dHi, i);
        int Dm1 = (i == 0) ? dL : MEXT(dLo, dHi, (i == 0 ? 0 : i - 1));
        int Dp1 = (i == 7) ? dR : MEXT(dLo, dHi, (i == 7 ? 7 : i + 1));
        // dir0:(0,-1) dir1:(-1,0) dir2:(-1,-1) dir3:(-1,+1); n1=+d1, n2=-d1
        int n1 = (dir == 0) ? Om1 : (dir == 1) ? Ui : (dir == 2) ? Um1 : Up1;
        int n2 = (dir == 0) ? Op1 : (dir == 1) ? Di : (dir == 2) ? Dp1 : Dm1;
        bool keep = (m > n1) && (m >= n2);
        if (keep && m > 200) sb |= 1u << i;
        if (keep && m > 100) wb |= 1u << i;
    }

    const int src = (lane & 7) << 3;
    uint64_t wordS = 0, wordW = 0;
    #pragma unroll
    for (int i = 0; i < 8; ++i) {
        wordS |= (uint64_t)(uint32_t)__shfl((int)sb, src + i, 64) << (i * 8);
        wordW |= (uint64_t)(uint32_t)__shfl((int)wb, src + i, 64) << (i * 8);
    }
    if (lane < 8)       strongB[y * WPR + lane] = wordS;
    else if (lane < 16) weakB[y * WPR + (lane - 8)] = wordW;
}

// Kernel 3: ALL hysteresis rounds in ONE kernel (verbatim round-5 verified).
__global__ void __launch_bounds__(256) k_hyst(
        const unsigned long long* __restrict__ weakB,
        unsigned long long* __restrict__ buf,
        int* __restrict__ flags)
{
    const int lane = threadIdx.x & 63;
    const int wave = (blockIdx.x << 2) + (threadIdx.x >> 6);   // 0..127
    const int base = ((wave << 6) + lane) * WPR;               // own row

    uint64_t own[8], wk[8];
    #pragma unroll
    for (int k = 0; k < 8; ++k) { wk[k] = weakB[base + k]; own[k] = buf[base + k]; }

    uint64_t hspu[8], hspd[8];
    #pragma unroll
    for (int k = 0; k < 8; ++k) { hspu[k] = 0; hspd[k] = 0; }

    auto load_halo = [&]() {
        uint64_t h[8];
        if (lane == 0 && wave > 0) {
            #pragma unroll
            for (int k = 0; k < 8; ++k) h[k] = cload64(&buf[base - WPR + k]);
            #pragma unroll
            for (int k = 0; k < 8; ++k) {
                uint64_t a = h[k] | (h[k] << 1) | (h[k] >> 1);
                if (k > 0) a |= h[k - 1] >> 63;
                if (k < 7) a |= h[k + 1] << 63;
                hspu[k] = a;
            }
        }
        if (lane == 63 && wave < 127) {
            #pragma unroll
            for (int k = 0; k < 8; ++k) h[k] = cload64(&buf[base + WPR + k]);
            #pragma unroll
            for (int k = 0; k < 8; ++k) {
                uint64_t a = h[k] | (h[k] << 1) | (h[k] >> 1);
                if (k > 0) a |= h[k - 1] >> 63;
                if (k < 7) a |= h[k + 1] << 63;
                hspd[k] = a;
            }
        }
    };
    load_halo();

    bool grewAny = false;
    for (int r = 0; r < NROUND; ++r) {
        bool grew = false;
        for (;;) {
            uint64_t sp[8];
            #pragma unroll
            for (int k = 0; k < 8; ++k) {
                uint64_t h = own[k] | (own[k] << 1) | (own[k] >> 1);
                if (k > 0) h |= own[k - 1] >> 63;
                if (k < 7) h |= own[k + 1] << 63;
                sp[k] = h;
            }
            uint64_t su[8], sd[8];
            #pragma unroll
            for (int k = 0; k < 8; ++k) {
                su[k] = shfl_up64(sp[k], 1);
                sd[k] = shfl_dn64(sp[k], 1);
            }
            if (lane == 0) {
                #pragma unroll
                for (int k = 0; k < 8; ++k) su[k] = hspu[k];
            }
            if (lane == 63) {
                #pragma unroll
                for (int k = 0; k < 8; ++k) sd[k] = hspd[k];
            }
            uint32_t ch = 0;
            #pragma unroll
            for (int k = 0; k < 8; ++k) {
                uint64_t acc = sp[k] | su[k] | sd[k];
                uint64_t nv = runfill(own[k] | (acc & wk[k]), wk[k]);
                ch |= (uint32_t)(nv != own[k]);
                own[k] = nv;
            }
            if (ch) grew = true;
            if (__ballot(ch ? 1 : 0) == 0ull) break;   // wave-uniform
        }
        grewAny |= grew;

        if (grew && lane == 0)
            __hip_atomic_store(&flags[r], 1, __ATOMIC_RELAXED, __HIP_MEMORY_SCOPE_AGENT);
        if (lane == 0 || lane == 63) {
            #pragma unroll
            for (int k = 0; k < 8; ++k) cstore64(&buf[base + k], own[k]);
        }
        __syncthreads();
        if (threadIdx.x == 0) {
            __hip_atomic_fetch_add(&flags[8 + r], 1, __ATOMIC_RELAXED, __HIP_MEMORY_SCOPE_AGENT);
            while (__hip_atomic_load(&flags[8 + r], __ATOMIC_RELAXED, __HIP_MEMORY_SCOPE_AGENT) < NBLK)
                __builtin_amdgcn_s_sleep(2);
        }
        __syncthreads();

        if (__hip_atomic_load(&flags[r], __ATOMIC_RELAXED, __HIP_MEMORY_SCOPE_AGENT) == 0)
            break;
        if (r + 1 < NROUND) load_halo();
    }

    if (__ballot(grewAny ? 1 : 0) != 0ull) {
        #pragma unroll
        for (int k = 0; k < 8; ++k) buf[base + k] = own[k];
    }
}

// Kernel 4: expand bitmap -> (16,3,512,512) f32 output in {-1,+1}, float4.
__global__ void k_out(const unsigned long long* __restrict__ result, float* __restrict__ out) {
    int t = blockIdx.x * blockDim.x + threadIdx.x;
    int b = t >> 16;
    int r = t & 65535;
    int h = r >> 7;
    int w = (r & 127) << 2;
    int y = (b << 9) + h;
    unsigned long long word = result[y * WPR + (w >> 6)];
    int sh = w & 63;
    float4 v;
    v.x = ((word >> (sh + 0)) & 1ull) ? 1.0f : -1.0f;
    v.y = ((word >> (sh + 1)) & 1ull) ? 1.0f : -1.0f;
    v.z = ((word >> (sh + 2)) & 1ull) ? 1.0f : -1.0f;
    v.w = ((word >> (sh + 3)) & 1ull) ? 1.0f : -1.0f;
    int base = (b * 3) << 18;
    int off = (h << 9) + w;
    *(float4*)&out[base + off] = v;
    *(float4*)&out[base + 262144 + off] = v;
    *(float4*)&out[base + 524288 + off] = v;
}

extern "C" void kernel_launch(void* const* d_in, const int* in_sizes, int n_in,
                              void* d_out, int out_size, void* d_ws, size_t ws_size,
                              hipStream_t stream) {
    const float* x = (const float*)d_in[0];
    float* out = (float*)d_out;
    char* ws = (char*)d_ws;

    uint16_t* packed          = (uint16_t*)(ws);
    unsigned long long* buf   = (unsigned long long*)(ws + 8388608);
    unsigned long long* weakB = (unsigned long long*)(ws + 8912896);
    int* flags                = (int*)(ws + 9437184);

    k_sobel<<<2048, 256, 0, stream>>>(x, packed);
    k_nms<<<2048, 256, 0, stream>>>(packed, buf, weakB, flags);
    k_hyst<<<NBLK, 256, 0, stream>>>(weakB, buf, flags);
    k_out<<<4096, 256, 0, stream>>>(buf, out);
}